// Round 18
// baseline (496.281 us; speedup 1.0000x reference)
//
#include <hip/hip_runtime.h>
#include <hip/hip_bf16.h>

typedef unsigned short u16;
typedef unsigned int u32;

typedef short bf16v8 __attribute__((ext_vector_type(8)));
typedef float f32v4 __attribute__((ext_vector_type(4)));

// ---------------- problem constants ----------------
constexpr int BB   = 64;
constexpr int TT   = 196;
constexpr int NTOK = BB * TT;   // 12544
constexpr int DD   = 512;
constexpr int FF   = 2048;
constexpr int EE   = 8;
constexpr int NBR  = 2;
constexpr int GE   = NBR * EE;  // 16 global experts
constexpr int MT128 = 212;      // >= max total 128-row tiles (<=210)
// front_trans grid: [0,256) w1 128-col slabs; [256,512) w2 quarter-slabs; [512,516) out_w
constexpr int NB_TRANS = 516;
// front_misc grid: [0,64) eo; [64, 64+NTOK/4) ln_gate
constexpr int NB_MISC = 64 + NTOK / 4;

__device__ __forceinline__ u16 f2bf(float f) {
    union { float f; u32 u; } v; v.f = f;
    u32 r = v.u + 0x7fffu + ((v.u >> 16) & 1u);
    return (u16)(r >> 16);
}

__device__ __forceinline__ float bf2f(u32 u) {
    union { u32 u; float f; } v; v.u = u << 16; return v.f;
}

__device__ __forceinline__ float wave_sum(float v) {
    #pragma unroll
    for (int m = 32; m > 0; m >>= 1) v += __shfl_xor(v, m, 64);
    return v;
}

// tanh-approx gelu via sigmoid: gelu(v) = v * sigmoid(1.596v + 0.0714v^3)
__device__ __forceinline__ float gelu_tanh(float v) {
    float y = 1.595769122f * v + 0.071354816f * (v * v * v);
    return v / (1.0f + __expf(-y));
}

__device__ __forceinline__ float silu(float v) {
    return v / (1.0f + __expf(-v));
}

__device__ __forceinline__ void gload16(const u16* g, u16* l) {
    typedef const __attribute__((address_space(1))) unsigned gv_t;
    typedef __attribute__((address_space(3))) unsigned lv_t;
    __builtin_amdgcn_global_load_lds((gv_t*)g, (lv_t*)l, 16, 0, 0);
}

__device__ __forceinline__ void bar() {
    asm volatile("" ::: "memory");
    __builtin_amdgcn_s_barrier();
    asm volatile("" ::: "memory");
}

#define ASM_VMCNT4 asm volatile("s_waitcnt vmcnt(4)" ::: "memory")
#define ASM_VMCNT0 asm volatile("s_waitcnt vmcnt(0)" ::: "memory")
#define ASM_LGKM0  asm volatile("s_waitcnt lgkmcnt(0)" ::: "memory")

// ---------------- front_misc: eo GEMM + ln_gate ------------------------------
__global__ __launch_bounds__(256) void front_misc_kernel(
    const float* __restrict__ emb, const float* __restrict__ emb_w,
    const float* __restrict__ emb_b, float* __restrict__ eo,
    const float* __restrict__ x, const float* __restrict__ ln_g,
    const float* __restrict__ ln_b, const float* __restrict__ gate_w,
    const float* __restrict__ gate_b,
    u16* __restrict__ hA, u16* __restrict__ hB,
    int* __restrict__ idxb, float* __restrict__ pbuf)
{
    __shared__ __align__(16) float se[4 * DD];
    int id = blockIdx.x;
    int t = threadIdx.x;

    if (id >= 64) {                // ---- ln_gate: 4 tokens per block ----
        int wave = t >> 6, lane = t & 63;
        int tok = (id - 64) * 4 + wave;
        const float* xr = x + (size_t)tok * DD + lane * 8;
        float4 v0 = *(const float4*)xr;
        float4 v1 = *(const float4*)(xr + 4);
        float xs[8] = {v0.x, v0.y, v0.z, v0.w, v1.x, v1.y, v1.z, v1.w};
        float s = 0.f, ss = 0.f;
        #pragma unroll
        for (int i = 0; i < 8; ++i) { s += xs[i]; ss += xs[i] * xs[i]; }
        s = wave_sum(s); ss = wave_sum(ss);
        float mu = s * (1.0f / DD);
        float var = ss * (1.0f / DD) - mu * mu;
        float rstd = rsqrtf(var + 1e-5f);

        #pragma unroll
        for (int br = 0; br < NBR; ++br) {
            u16* hb = br ? hB : hA;
            float part[8] = {0, 0, 0, 0, 0, 0, 0, 0};
            u16 hu[8];
            #pragma unroll
            for (int i = 0; i < 8; ++i) {
                int d = lane * 8 + i;
                float g = ln_g[br * DD + d], b = ln_b[br * DD + d];
                float h = (xs[i] - mu) * rstd * g + b;
                hu[i] = f2bf(h);
                const float* gw = gate_w + ((size_t)br * DD + d) * EE;
                float4 g0 = *(const float4*)gw;
                float4 g1 = *(const float4*)(gw + 4);
                part[0] += h * g0.x; part[1] += h * g0.y; part[2] += h * g0.z; part[3] += h * g0.w;
                part[4] += h * g1.x; part[5] += h * g1.y; part[6] += h * g1.z; part[7] += h * g1.w;
            }
            uint4 pk;
            pk.x = (u32)hu[0] | ((u32)hu[1] << 16);
            pk.y = (u32)hu[2] | ((u32)hu[3] << 16);
            pk.z = (u32)hu[4] | ((u32)hu[5] << 16);
            pk.w = (u32)hu[6] | ((u32)hu[7] << 16);
            *(uint4*)(hb + (size_t)tok * DD + lane * 8) = pk;

            float logit[8];
            #pragma unroll
            for (int e = 0; e < 8; ++e)
                logit[e] = wave_sum(part[e]) + gate_b[br * EE + e];
            float m = logit[0]; int bi = 0;
            #pragma unroll
            for (int e = 1; e < 8; ++e)
                if (logit[e] > m) { m = logit[e]; bi = e; }
            float sum = 0.f;
            #pragma unroll
            for (int e = 0; e < 8; ++e) sum += __expf(logit[e] - m);
            if (lane == 0) {
                idxb[br * NTOK + tok] = bi;
                pbuf[br * NTOK + tok] = 1.0f / sum;
            }
        }
        return;
    }

    // ---- eo: silu(emb) @ emb_w + emb_b ----
    int cg = id & 3, bg = id >> 2;
    int b0 = bg * 4;
    int c0 = cg * 256 + t;
    for (int i = t; i < 4 * DD; i += 256) {
        int b = i >> 9, d = i & (DD - 1);
        se[b * DD + d] = silu(emb[(size_t)(b0 + b) * DD + d]);
    }
    __syncthreads();
    float acc[4] = {0, 0, 0, 0};
    for (int k = 0; k < DD; ++k) {
        float wv = emb_w[(size_t)k * 1024 + c0];
        #pragma unroll
        for (int b = 0; b < 4; ++b) acc[b] += se[b * DD + k] * wv;
    }
    float bb = emb_b[c0];
    #pragma unroll
    for (int b = 0; b < 4; ++b)
        eo[(size_t)(b0 + b) * 1024 + c0] = acc[b] + bb;
}

// ---------------- front_trans: slab transposes + cnt init --------------------
// Blocks own 128-col slabs: per source row they read 512B contiguous into two
// side-by-side [64][69] tiles, register prefetch of next row-band covers pack.
__global__ __launch_bounds__(256) void front_trans_kernel(
    const float* __restrict__ w1, u16* __restrict__ w1t,
    const float* __restrict__ w2, u16* __restrict__ w2t,
    const float* __restrict__ ow, u16* __restrict__ owt,
    int* __restrict__ cnt)
{
    __shared__ __align__(16) float smem[2 * 64 * 69];
    int id = blockIdx.x;
    int t = threadIdx.x;

    if (id == 0 && t < 16) cnt[t] = 0;

    const float* src; u16* dst; int C, Rfull, rowbase, c0;
    const int NIT = 8;
    if (id < 256) {                // w1: src [512][2048], dst [2048][512]
        int e = id >> 4, cg = id & 15;
        src = w1 + (size_t)e * DD * FF; dst = w1t + (size_t)e * FF * DD;
        C = FF; Rfull = DD; rowbase = 0; c0 = cg * 128;
    } else if (id < 512) {         // w2: src [2048][512], dst [512][2048], quarter-slabs
        int sid = id - 256; int e = sid >> 4, rem = sid & 15;
        src = w2 + (size_t)e * FF * DD; dst = w2t + (size_t)e * FF * DD;
        C = DD; Rfull = FF; rowbase = (rem >> 2) * 512; c0 = (rem & 3) * 128;
    } else {                       // out_w: [512][512]
        int cg = id - 512;
        src = ow; dst = owt;
        C = DD; Rfull = DD; rowbase = 0; c0 = cg * 128;
    }

    float (*tile)[64][69] = (float (*)[64][69])smem;   // two tiles, 35.3 KB
    int tx = t & 15, ty = t >> 4;
    int wc = t & 7, wr0 = t >> 3;

    // prologue: load row-band 0 into registers (512B contiguous per row)
    float4 v0[4], v1[4];
    #pragma unroll
    for (int j = 0; j < 4; ++j) {
        const float* rp = &src[(size_t)(rowbase + ty + 16 * j) * C + c0];
        v0[j] = *(const float4*)(rp + tx * 4);
        v1[j] = *(const float4*)(rp + 64 + tx * 4);
    }

    for (int it = 0; it < NIT; ++it) {
        // write current row-band into the two tiles
        #pragma unroll
        for (int j = 0; j < 4; ++j) {
            int row = ty + 16 * j;
            tile[0][row][tx * 4 + 0] = v0[j].x;
            tile[0][row][tx * 4 + 1] = v0[j].y;
            tile[0][row][tx * 4 + 2] = v0[j].z;
            tile[0][row][tx * 4 + 3] = v0[j].w;
            tile[1][row][tx * 4 + 0] = v1[j].x;
            tile[1][row][tx * 4 + 1] = v1[j].y;
            tile[1][row][tx * 4 + 2] = v1[j].z;
            tile[1][row][tx * 4 + 3] = v1[j].w;
        }
        __syncthreads();

        // prefetch next row-band into registers (covered by pack below)
        if (it + 1 < NIT) {
            #pragma unroll
            for (int j = 0; j < 4; ++j) {
                const float* rp = &src[(size_t)(rowbase + (it + 1) * 64 + ty + 16 * j) * C + c0];
                v0[j] = *(const float4*)(rp + tx * 4);
                v1[j] = *(const float4*)(rp + 64 + tx * 4);
            }
        }

        // pack + store both tiles (128B contiguous per dst row per iter)
        #pragma unroll
        for (int half = 0; half < 2; ++half) {
            #pragma unroll
            for (int p = 0; p < 2; ++p) {
                int cc = wr0 + p * 32;
                u16 pk[8];
                #pragma unroll
                for (int i = 0; i < 8; ++i)
                    pk[i] = f2bf(tile[half][wc * 8 + i][cc]);
                uint4 vv;
                vv.x = (u32)pk[0] | ((u32)pk[1] << 16);
                vv.y = (u32)pk[2] | ((u32)pk[3] << 16);
                vv.z = (u32)pk[4] | ((u32)pk[5] << 16);
                vv.w = (u32)pk[6] | ((u32)pk[7] << 16);
                *(uint4*)&dst[(size_t)(c0 + half * 64 + cc) * Rfull + rowbase + it * 64 + wc * 8] = vv;
            }
        }
        __syncthreads();
    }
}

// ---------------- routing: LDS histogram, 16 global atomics per block -------
__global__ __launch_bounds__(256) void route_kernel(
    const int* __restrict__ idxb, int* __restrict__ cnt, int* __restrict__ list)
{
    __shared__ int lcnt[GE];
    __shared__ int gbase[GE];
    int tid = threadIdx.x;
    int t = blockIdx.x * 256 + tid;
    if (tid < GE) lcnt[tid] = 0;
    __syncthreads();
    int e0 = idxb[t];
    int e1 = EE + idxb[NTOK + t];
    int r0 = atomicAdd(&lcnt[e0], 1);
    int r1 = atomicAdd(&lcnt[e1], 1);
    __syncthreads();
    if (tid < GE) {
        int c = lcnt[tid];
        gbase[tid] = c ? atomicAdd(&cnt[tid], c) : 0;
    }
    __syncthreads();
    list[(size_t)e0 * NTOK + gbase[e0] + r0] = t;
    list[(size_t)e1 * NTOK + gbase[e1] + r1] = t;
}

// ---------------- tile table (128-row granular) -----------------------------
__global__ void tilestart_kernel(const int* __restrict__ cnt, int* __restrict__ meta)
{
    int lane = threadIdx.x;   // 64 threads
    if (lane < 16) {
        int pbv = 0;
        for (int k = 0; k < lane; ++k) pbv += cnt[k];
        meta[lane] = pbv;
    }
    if (lane == 16) {
        int n = 0;
        for (int k = 0; k < 16; ++k) n += (cnt[k] + 127) >> 7;
        meta[33] = n;
    }
    for (int j = lane; j < MT128; j += 64) {
        int ge = -1, start = 0, tt = 0;
        #pragma unroll
        for (int k = 0; k < 16; ++k) {
            int mt = (cnt[k] + 127) >> 7;
            if (ge < 0) {
                if (j < start + mt) { ge = k; tt = j - start; }
                else start += mt;
            }
        }
        if (ge >= 0) meta[64 + j] = (ge << 20) | tt;
    }
}

// ---------------- 128x128 MFMA GEMM, BK=32, dbuf, counted vmcnt, 4 blk/CU ---
// Epilogue: LDS repack -> coalesced 16B stores (128B segments per row).
// MODE 0: u[pos] = gelu(h[tok] @ W1[ge] + b1[ge])      A gathered via list
// MODE 1: moe{plane}[tok] = p * (u[pos] @ W2[ge] + b2) A dense, bf16 out
template<int MODE>
__global__ __launch_bounds__(256, 4) void gemm_tile(
    const u16* __restrict__ A0, const u16* __restrict__ A1,
    const u16* __restrict__ Bt,
    const int* __restrict__ meta, const int* __restrict__ cnt,
    const int* __restrict__ list, const float* __restrict__ pbuf,
    const float* __restrict__ bias,
    u16* __restrict__ uout, u16* __restrict__ moeout)
{
    constexpr int K = (MODE == 1) ? FF : DD;
    constexpr int N = (MODE == 0) ? FF : DD;
    constexpr int NSTEP = K / 32;

    __shared__ __align__(16) u16 As[2][128 * 32];
    __shared__ __align__(16) u16 Bs[2][128 * 32];
    __shared__ int rowtok[128];
    __shared__ float rowp[128];

    int ntile = blockIdx.x;
    int j = blockIdx.y;
    if (j >= meta[33]) return;
    int ev = meta[64 + j];
    int ge = ev >> 20;
    int rb = (ev & 0xfffff) << 7;
    int cnt_e = cnt[ge];
    int pb = meta[ge];

    int tid = threadIdx.x, wave = tid >> 6, lane = tid & 63;
    int wm = wave >> 1, wn = wave & 1;
    int fr = lane & 15, fq = lane >> 4;
    int r0 = wave * 16 + (lane >> 2);
    int sc = (lane & 3) ^ ((lane >> 3) & 3);   // swizzled source chunk (bank fix)

    const u16* Abase;
    if constexpr (MODE == 0) Abase = (ge >= 8) ? A1 : A0;
    else                     Abase = A0;
    const u16* Bte = Bt + (size_t)ge * FF * DD;

    const u16 *aSrc0, *aSrc1, *bSrc0, *bSrc1;
    if constexpr (MODE == 0) {
        int lb = ge * NTOK;
        int g0 = rb + r0, g1 = g0 + 64;
        int t0 = (g0 < cnt_e) ? list[lb + g0] : list[lb];
        int t1 = (g1 < cnt_e) ? list[lb + g1] : list[lb];
        aSrc0 = Abase + (size_t)t0 * K + sc * 8;
        aSrc1 = Abase + (size_t)t1 * K + sc * 8;
    } else {
        size_t base = (size_t)(pb + rb);
        aSrc0 = Abase + (base + r0) * (size_t)K + sc * 8;
        aSrc1 = Abase + (base + r0 + 64) * (size_t)K + sc * 8;
    }
    {
        int nrow = ntile * 128 + r0;
        bSrc0 = Bte + (size_t)nrow * K + sc * 8;
        bSrc1 = Bte + (size_t)(nrow + 64) * K + sc * 8;
    }

    if constexpr (MODE == 1) {
        if (tid < 128) {
            int g = rb + tid;
            int tk = (g < cnt_e) ? list[ge * NTOK + g] : -1;
            rowtok[tid] = tk;
            rowp[tid] = (tk >= 0) ? pbuf[(ge >> 3) * NTOK + tk] : 0.f;
        }
        ASM_LGKM0;
    }

    f32v4 acc[4][4];
    #pragma unroll
    for (int mi = 0; mi < 4; ++mi)
        #pragma unroll
        for (int ni = 0; ni < 4; ++ni)
            acc[mi][ni] = (f32v4){0.f, 0.f, 0.f, 0.f};

    int ch = fq ^ ((fr >> 1) & 3);             // swizzled read chunk (bank fix)

    // ---- prologue: stage step 0 into buf 0 ----
    gload16(aSrc0, &As[0][wave * 512]);
    gload16(aSrc1, &As[0][2048 + wave * 512]);
    gload16(bSrc0, &Bs[0][wave * 512]);
    gload16(bSrc1, &Bs[0][2048 + wave * 512]);
    aSrc0 += 32; aSrc1 += 32; bSrc0 += 32; bSrc1 += 32;

    #pragma unroll 2
    for (int t = 0; t < NSTEP; ++t) {
        const int cur = t & 1;
        if (t + 1 < NSTEP) {
            gload16(aSrc0, &As[cur ^ 1][wave * 512]);
            gload16(aSrc1, &As[cur ^ 1][2048 + wave * 512]);
            gload16(bSrc0, &Bs[cur ^ 1][wave * 512]);
            gload16(bSrc1, &Bs[cur ^ 1][2048 + wave * 512]);
            aSrc0 += 32; aSrc1 += 32; bSrc0 += 32; bSrc1 += 32;
            ASM_VMCNT4;
        } else {
            ASM_VMCNT0;
        }
        bar();

        bf16v8 af[4], bfr[4];
        #pragma unroll
        for (int mi = 0; mi < 4; ++mi)
            af[mi] = *(const bf16v8*)&As[cur][(wm * 64 + mi * 16 + fr) * 32 + ch * 8];
        #pragma unroll
        for (int ni = 0; ni < 4; ++ni)
            bfr[ni] = *(const bf16v8*)&Bs[cur][(wn * 64 + ni * 16 + fr) * 32 + ch * 8];
        #pragma unroll
        for (int mi = 0; mi < 4; ++mi)
            #pragma unroll
            for (int ni = 0; ni < 4; ++ni)
                acc[mi][ni] = __builtin_amdgcn_mfma_f32_16x16x32_bf16(
                    af[mi], bfr[ni], acc[mi][ni], 0, 0, 0);
        bar();
    }

    // ---- epilogue: LDS repack -> coalesced 16B stores ----
    float bnv[4];
    #pragma unroll
    for (int ni = 0; ni < 4; ++ni)
        bnv[ni] = bias[(size_t)ge * N + ntile * 128 + wn * 64 + ni * 16 + fr];

    // halves: wm=0 waves -> As region, wm=1 waves -> Bs region; [16][133] f32
    float* halfw = (wm == 0) ? (float*)As : (float*)Bs;
    int rrd = tid >> 3;                     // 0..31: 0-15 from As, 16-31 from Bs
    const float* halfr = (rrd < 16) ? (const float*)As : (const float*)Bs;
    int lr = rrd & 15;
    int cb = (tid & 7) * 8;                 // col groups cb..cb+7 and cb+64..+71

    #pragma unroll
    for (int mi = 0; mi < 4; ++mi) {
        #pragma unroll
        for (int ni = 0; ni < 4; ++ni)
            #pragma unroll
            for (int r = 0; r < 4; ++r)
                halfw[(fq * 4 + r) * 133 + wn * 64 + ni * 16 + fr] =
                    acc[mi][ni][r] + bnv[ni];
        ASM_LGKM0;   // drain ds_writes before barrier (cross-thread RAW)
        bar();

        int grow = mi * 16 + lr + ((rrd >> 4) * 64);   // row within 128-tile
        float v0[8], v1[8];
        #pragma unroll
        for (int i = 0; i < 8; ++i) {
            v0[i] = halfr[lr * 133 + cb + i];
            v1[i] = halfr[lr * 133 + cb + 64 + i];
        }
        if constexpr (MODE == 0) {
            if (rb + grow < cnt_e) {
                u16 p0[8], p1[8];
                #pragma unroll
                for (int i = 0; i < 8; ++i) {
                    p0[i] = f2bf(gelu_tanh(v0[i]));
                    p1[i] = f2bf(gelu_tanh(v1[i]));
                }
                uint4 q0, q1;
                q0.x = (u32)p0[0] | ((u32)p0[1] << 16);
                q0.y = (u32)p0[2] | ((u32)p0[3] << 16);
                q0.z = (u32)p0[4] | ((u32)p0[5] << 16);
                q0.w = (u32)p0[6] | ((u32)p0[7] << 16);
                q1.x = (u32)p1[0] | ((u32)p1[1] << 16);
                q1.y = (u32)p1[2] | ((u32)p1[3] << 16);
                q1.z = (u32)p1[4] | ((u32)p1[5] << 16);
                q1.w = (u32)p1[6] | ((u32)p1[7] << 16);
                u16* orow = uout + (size_t)(pb + rb + grow) * FF + ntile * 128;
                *(uint4*)(orow + cb) = q0;
                *(uint4*)(orow + cb + 64) = q1;
            }
        } else {
            int tok = rowtok[grow];
            if (tok >= 0) {
                float p = rowp[grow];
                u16 p0[8], p1[8];
                #pragma unroll
                for (int i = 0; i < 8; ++i) {
                    p0[i] = f2bf(v0[i] * p);
                    p1[i] = f2bf(v1[i] * p);
                }
                uint4 q0, q1;
                q0.x = (u32)p0[0] | ((u32)p0[1] << 16);
                q0.y = (u32)p0[2] | ((u32)p0[3] << 16);
                q0.z = (u32)p0[4] | ((u32)p0[5] << 16);
                q0.w = (u32)p0[6] | ((u32)p0[7] << 16);
                q1.x = (u32)p1[0] | ((u32)p1[1] << 16);
                q1.y = (u32)p1[2] | ((u32)p1[3] << 16);
                q1.z = (u32)p1[4] | ((u32)p1[5] << 16);
                q1.w = (u32)p1[6] | ((u32)p1[7] << 16);
                u16* orow = moeout + ((size_t)(ge >> 3) * NTOK + tok) * DD + ntile * 128;
                *(uint4*)(orow + cb) = q0;
                *(uint4*)(orow + cb + 64) = q1;
            }
        }
        bar();
    }
}

// ---------------- 128x128 GEMM (output projection only) ---------------------
// dout = xres + A @ owt + out_b  (A dense bf16, f32 out, 64B segments OK)
__global__ __launch_bounds__(256, 4) void gemm_out(
    const u16* __restrict__ A0, const u16* __restrict__ Bt,
    const float* __restrict__ bias,
    const float* __restrict__ xres, float* __restrict__ dout)
{
    constexpr int K = DD;
    constexpr int NSTEP = K / 32;

    __shared__ __align__(16) u16 As[2][128 * 32];
    __shared__ __align__(16) u16 Bs[2][128 * 32];

    int ntile = blockIdx.x;
    int rb = blockIdx.y * 128;

    int tid = threadIdx.x, wave = tid >> 6, lane = tid & 63;
    int wm = wave >> 1, wn = wave & 1;
    int fr = lane & 15, fq = lane >> 4;
    int r0 = wave * 16 + (lane >> 2);
    int sc = (lane & 3) ^ ((lane >> 3) & 3);

    const u16 *aSrc0, *aSrc1, *bSrc0, *bSrc1;
    aSrc0 = A0 + (size_t)(rb + r0) * K + sc * 8;
    aSrc1 = A0 + (size_t)(rb + r0 + 64) * K + sc * 8;
    {
        int nrow = ntile * 128 + r0;
        bSrc0 = Bt + (size_t)nrow * K + sc * 8;
        bSrc1 = Bt + (size_t)(nrow + 64) * K + sc * 8;
    }

    f32v4 acc[4][4];
    #pragma unroll
    for (int mi = 0; mi < 4; ++mi)
        #pragma unroll
        for (int ni = 0; ni < 4; ++ni)
            acc[mi][ni] = (f32v4){0.f, 0.f, 0.f, 0.f};

    int ch = fq ^ ((fr >> 1) & 3);

    gload16(aSrc0, &As[0][wave * 512]);
    gload16(aSrc1, &As[0][2048 + wave * 512]);
    gload16(bSrc0, &Bs[0][wave * 512]);
    gload16(bSrc1, &Bs[0][2048 + wave * 512]);
    aSrc0 += 32; aSrc1 += 32; bSrc0 += 32; bSrc1 += 32;

    #pragma unroll 2
    for (int t = 0; t < NSTEP; ++t) {
        const int cur = t & 1;
        if (t + 1 < NSTEP) {
            gload16(aSrc0, &As[cur ^ 1][wave * 512]);
            gload16(aSrc1, &As[cur ^ 1][2048 + wave * 512]);
            gload16(bSrc0, &Bs[cur ^ 1][wave * 512]);
            gload16(bSrc1, &Bs[cur ^ 1][2048 + wave * 512]);
            aSrc0 += 32; aSrc1 += 32; bSrc0 += 32; bSrc1 += 32;
            ASM_VMCNT4;
        } else {
            ASM_VMCNT0;
        }
        bar();

        bf16v8 af[4], bfr[4];
        #pragma unroll
        for (int mi = 0; mi < 4; ++mi)
            af[mi] = *(const bf16v8*)&As[cur][(wm * 64 + mi * 16 + fr) * 32 + ch * 8];
        #pragma unroll
        for (int ni = 0; ni < 4; ++ni)
            bfr[ni] = *(const bf16v8*)&Bs[cur][(wn * 64 + ni * 16 + fr) * 32 + ch * 8];
        #pragma unroll
        for (int mi = 0; mi < 4; ++mi)
            #pragma unroll
            for (int ni = 0; ni < 4; ++ni)
                acc[mi][ni] = __builtin_amdgcn_mfma_f32_16x16x32_bf16(
                    af[mi], bfr[ni], acc[mi][ni], 0, 0, 0);
        bar();
    }

    #pragma unroll
    for (int mi = 0; mi < 4; ++mi) {
        #pragma unroll
        for (int ni = 0; ni < 4; ++ni) {
            int col = ntile * 128 + wn * 64 + ni * 16 + fr;
            float bn = bias[col];
            #pragma unroll
            for (int r = 0; r < 4; ++r) {
                int rr = wm * 64 + mi * 16 + fq * 4 + r;
                size_t o = (size_t)(rb + rr) * DD + col;
                dout[o] = xres[o] + acc[mi][ni][r] + bn;
            }
        }
    }
}

// ---------------- stylize: LN((moe0+moe1)/2)*(1+scale)+shift -> silu -> bf16
__global__ __launch_bounds__(256) void stylize_kernel(
    const u16* __restrict__ moe, const float* __restrict__ eo,
    const float* __restrict__ sn_g, const float* __restrict__ sn_b,
    u16* __restrict__ sbuf)
{
    int wave = threadIdx.x >> 6, lane = threadIdx.x & 63;
    int tok = blockIdx.x * 4 + wave;
    int b = tok / TT;
    const u16* mr = moe + (size_t)tok * DD + lane * 8;
    const u16* mr2 = mr + (size_t)NTOK * DD;
    uint4 pa = *(const uint4*)mr;
    uint4 pb = *(const uint4*)mr2;
    float os[8];
    os[0] = (bf2f(pa.x & 0xffff) + bf2f(pb.x & 0xffff)) * 0.5f;
    os[1] = (bf2f(pa.x >> 16)    + bf2f(pb.x >> 16))    * 0.5f;
    os[2] = (bf2f(pa.y & 0xffff) + bf2f(pb.y & 0xffff)) * 0.5f;
    os[3] = (bf2f(pa.y >> 16)    + bf2f(pb.y >> 16))    * 0.5f;
    os[4] = (bf2f(pa.z & 0xffff) + bf2f(pb.z & 0xffff)) * 0.5f;
    os[5] = (bf2f(pa.z >> 16)    + bf2f(pb.z >> 16))    * 0.5f;
    os[6] = (bf2f(pa.w & 0xffff) + bf2f(pb.w & 0xffff)) * 0.5f;
    os[7] = (bf2f(pa.w >> 16)    + bf2f(pb.w >> 16))    * 0.5f;
    float s = 0.f, ss = 0.f;
    #pragma unroll
    for (int i = 0; i < 8; ++i) { s += os[i]; ss += os[i] * os[i]; }
    s = wave_sum(s); ss = wave_sum(ss);
    float mu = s * (1.0f / DD);
    float var = ss * (1.0f / DD) - mu * mu;
    float rstd = rsqrtf(var + 1e-5f);
    u16 hu[8];
    #pragma unroll
    for (int i = 0; i < 8; ++i) {
        int d = lane * 8 + i;
        float h = (os[i] - mu) * rstd * sn_g[d] + sn_b[d];
        float scv = eo[(size_t)b * 1024 + d];
        float shv = eo[(size_t)b * 1024 + DD + d];
        h = h * (1.0f + scv) + shv;
        hu[i] = f2bf(silu(h));
    }
    uint4 pk;
    pk.x = (u32)hu[0] | ((u32)hu[1] << 16);
    pk.y = (u32)hu[2] | ((u32)hu[3] << 16);
    pk.z = (u32)hu[4] | ((u32)hu[5] << 16);
    pk.w = (u32)hu[6] | ((u32)hu[7] << 16);
    *(uint4*)(sbuf + (size_t)tok * DD + lane * 8) = pk;
}

// ---------------- host ----------------
extern "C" void kernel_launch(void* const* d_in, const int* in_sizes, int n_in,
                              void* d_out, int out_size, void* d_ws, size_t ws_size,
                              hipStream_t stream)
{
    const float* x      = (const float*)d_in[0];
    const float* emb    = (const float*)d_in[1];
    const float* ln_g   = (const float*)d_in[2];
    const float* ln_b   = (const float*)d_in[3];
    const float* gate_w = (const float*)d_in[4];
    const float* gate_b = (const float*)d_in[5];
    const float* w1     = (const float*)d_in[6];
    const float* b1     = (const float*)d_in[7];
    const float* w2     = (const float*)d_in[8];
    const float* b2     = (const float*)d_in[9];
    const float* emb_w  = (const float*)d_in[10];
    const float* emb_b  = (const float*)d_in[11];
    const float* sn_g   = (const float*)d_in[12];
    const float* sn_b   = (const float*)d_in[13];
    const float* out_w  = (const float*)d_in[14];
    const float* out_b  = (const float*)d_in[15];
    (void)n_in; (void)in_sizes; (void)out_size; (void)ws_size;

    const size_t szW    = (size_t)GE * FF * DD * 2;
    const size_t szOwt  = (size_t)DD * DD * 2;
    const size_t szH    = (size_t)NTOK * DD * 2;
    const size_t szEo   = (size_t)BB * 2 * DD * 4;
    const size_t szP    = (size_t)NBR * NTOK * 4;
    const size_t szCnt  = 256, szMeta = 4096;
    const size_t szList = (size_t)GE * NTOK * 4;
    const size_t szU    = ((size_t)2 * NTOK + 256) * FF * 2;
    const size_t szM    = (size_t)2 * NTOK * DD * 2;

    auto align256 = [](size_t v) { return (v + 255) & ~(size_t)255; };
    char* w = (char*)d_ws;
    size_t off = 0;
    auto take = [&](size_t bytes) -> void* {
        void* p = w + off;
        off = align256(off + bytes);
        return p;
    };
    u16*   w1t  = (u16*)take(szW);
    u16*   w2t  = (u16*)take(szW);
    u16*   owt  = (u16*)take(szOwt);
    u16*   hA   = (u16*)take(szH);       // reused as sbuf
    u16*   hB   = (u16*)take(szH);
    float* eo   = (float*)take(szEo);
    float* pbuf = (float*)take(szP);
    int*   idxb = (int*)take(szP);
    int*   cnt  = (int*)take(szCnt);
    int*   meta = (int*)take(szMeta);
    int*   list = (int*)take(szList);
    u16*   ubuf = (u16*)take(szU);
    u16*   moe  = (u16*)take(szM);

    // 1a. misc front: eo + LN/gate (separate dispatch for attribution + icache)
    front_misc_kernel<<<NB_MISC, 256, 0, stream>>>(emb, emb_w, emb_b, eo,
                                                   x, ln_g, ln_b, gate_w, gate_b,
                                                   hA, hB, idxb, pbuf);

    // 1b. weight transposes + cnt init
    front_trans_kernel<<<NB_TRANS, 256, 0, stream>>>(w1, w1t, w2, w2t,
                                                     out_w, owt, cnt);

    // 2. routing (LDS histogram) + tile table
    route_kernel<<<NTOK / 256, 256, 0, stream>>>(idxb, cnt, list);
    tilestart_kernel<<<1, 64, 0, stream>>>(cnt, meta);

    // 3. expert FFN (flat tile queues, ntile-fastest)
    gemm_tile<0><<<dim3(FF / 128, MT128), 256, 0, stream>>>(
        hA, hB, w1t, meta, cnt, list, nullptr, b1, ubuf, nullptr);
    gemm_tile<1><<<dim3(DD / 128, MT128), 256, 0, stream>>>(
        ubuf, nullptr, w2t, meta, cnt, list, pbuf, b2, nullptr, moe);

    // 4. stylization + output projection + residual
    stylize_kernel<<<NTOK / 4, 256, 0, stream>>>(moe, eo, sn_g, sn_b, hA);
    gemm_out<<<dim3(DD / 128, NTOK / 128), 256, 0, stream>>>(
        hA, owt, out_b, x, (float*)d_out);
}

// Round 19
// 313.122 us; speedup vs baseline: 1.5849x; 1.5849x over previous
//
#include <hip/hip_runtime.h>
#include <hip/hip_bf16.h>

typedef unsigned short u16;
typedef unsigned int u32;

typedef short bf16v8 __attribute__((ext_vector_type(8)));
typedef float f32v4 __attribute__((ext_vector_type(4)));

// ---------------- problem constants ----------------
constexpr int BB   = 64;
constexpr int TT   = 196;
constexpr int NTOK = BB * TT;   // 12544
constexpr int DD   = 512;
constexpr int FF   = 2048;
constexpr int EE   = 8;
constexpr int NBR  = 2;
constexpr int GE   = NBR * EE;  // 16 global experts
constexpr int MT128 = 212;      // >= max total 128-row tiles (<=210)
// front grid: [0,256) w1 128-col slabs; [256,512) w2 quarter-slabs;
//             [512,516) out_w; [516,580) eo; [580, 580+NTOK/4) ln_gate
constexpr int NB_FRONT = 580 + NTOK / 4;

__device__ __forceinline__ u16 f2bf(float f) {
    union { float f; u32 u; } v; v.f = f;
    u32 r = v.u + 0x7fffu + ((v.u >> 16) & 1u);
    return (u16)(r >> 16);
}

__device__ __forceinline__ float bf2f(u32 u) {
    union { u32 u; float f; } v; v.u = u << 16; return v.f;
}

__device__ __forceinline__ float wave_sum(float v) {
    #pragma unroll
    for (int m = 32; m > 0; m >>= 1) v += __shfl_xor(v, m, 64);
    return v;
}

// tanh-approx gelu via sigmoid: gelu(v) = v * sigmoid(1.596v + 0.0714v^3)
__device__ __forceinline__ float gelu_tanh(float v) {
    float y = 1.595769122f * v + 0.071354816f * (v * v * v);
    return v / (1.0f + __expf(-y));
}

__device__ __forceinline__ float silu(float v) {
    return v / (1.0f + __expf(-v));
}

__device__ __forceinline__ void gload16(const u16* g, u16* l) {
    typedef const __attribute__((address_space(1))) unsigned gv_t;
    typedef __attribute__((address_space(3))) unsigned lv_t;
    __builtin_amdgcn_global_load_lds((gv_t*)g, (lv_t*)l, 16, 0, 0);
}

__device__ __forceinline__ void bar() {
    asm volatile("" ::: "memory");
    __builtin_amdgcn_s_barrier();
    asm volatile("" ::: "memory");
}

#define ASM_VMCNT4 asm volatile("s_waitcnt vmcnt(4)" ::: "memory")
#define ASM_VMCNT0 asm volatile("s_waitcnt vmcnt(0)" ::: "memory")
#define ASM_LGKM0  asm volatile("s_waitcnt lgkmcnt(0)" ::: "memory")

// ---------------- merged front: slab transposes + eo + cnt init + ln_gate ---
// Transpose blocks own 128-col slabs (512B contiguous reads). eo/ln_gate
// branches restructured for load ILP (batched independent float4 loads).
__global__ __launch_bounds__(256) void front_kernel(
    const float* __restrict__ w1, u16* __restrict__ w1t,
    const float* __restrict__ w2, u16* __restrict__ w2t,
    const float* __restrict__ ow, u16* __restrict__ owt,
    const float* __restrict__ emb, const float* __restrict__ emb_w,
    const float* __restrict__ emb_b, float* __restrict__ eo,
    int* __restrict__ cnt,
    const float* __restrict__ x, const float* __restrict__ ln_g,
    const float* __restrict__ ln_b, const float* __restrict__ gate_w,
    const float* __restrict__ gate_b,
    u16* __restrict__ hA, u16* __restrict__ hB,
    int* __restrict__ idxb, float* __restrict__ pbuf)
{
    __shared__ __align__(16) float smem[2 * 64 * 69];
    int id = blockIdx.x;
    int t = threadIdx.x;

    if (id >= 580) {               // ---- ln_gate: 4 tokens per block ----
        int wave = t >> 6, lane = t & 63;
        int tok = (id - 580) * 4 + wave;
        const float* xr = x + (size_t)tok * DD + lane * 8;
        float4 v0 = *(const float4*)xr;
        float4 v1 = *(const float4*)(xr + 4);
        float xs[8] = {v0.x, v0.y, v0.z, v0.w, v1.x, v1.y, v1.z, v1.w};
        float s = 0.f, ss = 0.f;
        #pragma unroll
        for (int i = 0; i < 8; ++i) { s += xs[i]; ss += xs[i] * xs[i]; }
        s = wave_sum(s); ss = wave_sum(ss);
        float mu = s * (1.0f / DD);
        float var = ss * (1.0f / DD) - mu * mu;
        float rstd = rsqrtf(var + 1e-5f);

        #pragma unroll
        for (int br = 0; br < NBR; ++br) {
            u16* hb = br ? hB : hA;
            int pbase = br * DD + lane * 8;
            // batched independent param loads (float4 pairs, contiguous/lane)
            float4 ga0 = *(const float4*)&ln_g[pbase];
            float4 ga1 = *(const float4*)&ln_g[pbase + 4];
            float4 bb0 = *(const float4*)&ln_b[pbase];
            float4 bb1 = *(const float4*)&ln_b[pbase + 4];
            float gv[8] = {ga0.x, ga0.y, ga0.z, ga0.w, ga1.x, ga1.y, ga1.z, ga1.w};
            float bv[8] = {bb0.x, bb0.y, bb0.z, bb0.w, bb1.x, bb1.y, bb1.z, bb1.w};

            float hs[8];
            u16 hu[8];
            #pragma unroll
            for (int i = 0; i < 8; ++i) {
                hs[i] = (xs[i] - mu) * rstd * gv[i] + bv[i];
                hu[i] = f2bf(hs[i]);
            }
            uint4 pk;
            pk.x = (u32)hu[0] | ((u32)hu[1] << 16);
            pk.y = (u32)hu[2] | ((u32)hu[3] << 16);
            pk.z = (u32)hu[4] | ((u32)hu[5] << 16);
            pk.w = (u32)hu[6] | ((u32)hu[7] << 16);
            *(uint4*)(hb + (size_t)tok * DD + lane * 8) = pk;

            // gate: per-lane 256B contiguous gate_w rows, fully unrolled batch
            const float* gwb = gate_w + (size_t)pbase * EE;
            float part[8] = {0, 0, 0, 0, 0, 0, 0, 0};
            #pragma unroll
            for (int i = 0; i < 8; ++i) {
                float4 g0 = *(const float4*)(gwb + i * 8);
                float4 g1 = *(const float4*)(gwb + i * 8 + 4);
                float h = hs[i];
                part[0] += h * g0.x; part[1] += h * g0.y;
                part[2] += h * g0.z; part[3] += h * g0.w;
                part[4] += h * g1.x; part[5] += h * g1.y;
                part[6] += h * g1.z; part[7] += h * g1.w;
            }

            float logit[8];
            #pragma unroll
            for (int e = 0; e < 8; ++e)
                logit[e] = wave_sum(part[e]) + gate_b[br * EE + e];
            float m = logit[0]; int bi = 0;
            #pragma unroll
            for (int e = 1; e < 8; ++e)
                if (logit[e] > m) { m = logit[e]; bi = e; }
            float sum = 0.f;
            #pragma unroll
            for (int e = 0; e < 8; ++e) sum += __expf(logit[e] - m);
            if (lane == 0) {
                idxb[br * NTOK + tok] = bi;
                pbuf[br * NTOK + tok] = 1.0f / sum;
            }
        }
        return;
    }

    if (id >= 516) {               // ---- eo: silu(emb) @ emb_w + emb_b ----
        float* se = smem;          // [4][DD]
        int id2 = id - 516;
        int cg = id2 & 3, bg = id2 >> 2;
        int b0 = bg * 4;
        int c0 = cg * 256 + t;
        for (int i = t; i < 4 * DD; i += 256) {
            int b = i >> 9, d = i & (DD - 1);
            se[b * DD + d] = silu(emb[(size_t)(b0 + b) * DD + d]);
        }
        __syncthreads();
        float acc[4] = {0, 0, 0, 0};
        #pragma unroll 8
        for (int k = 0; k < DD; ++k) {
            float wv = emb_w[(size_t)k * 1024 + c0];
            #pragma unroll
            for (int b = 0; b < 4; ++b) acc[b] += se[b * DD + k] * wv;
        }
        float bb = emb_b[c0];
        #pragma unroll
        for (int b = 0; b < 4; ++b)
            eo[(size_t)(b0 + b) * 1024 + c0] = acc[b] + bb;
        return;
    }

    // ---- slab transpose f32[R][C] -> bf16[C][R], 128-col slabs ----
    if (id == 0 && t < 16) cnt[t] = 0;

    const float* src; u16* dst; int C, Rfull, rowbase, c0;
    const int NIT = 8;
    if (id < 256) {                // w1: src [512][2048], dst [2048][512]
        int e = id >> 4, cg = id & 15;
        src = w1 + (size_t)e * DD * FF; dst = w1t + (size_t)e * FF * DD;
        C = FF; Rfull = DD; rowbase = 0; c0 = cg * 128;
    } else if (id < 512) {         // w2: src [2048][512], dst [512][2048], quarter-slabs
        int sid = id - 256; int e = sid >> 4, rem = sid & 15;
        src = w2 + (size_t)e * FF * DD; dst = w2t + (size_t)e * FF * DD;
        C = DD; Rfull = FF; rowbase = (rem >> 2) * 512; c0 = (rem & 3) * 128;
    } else {                       // out_w: [512][512]
        int cg = id - 512;
        src = ow; dst = owt;
        C = DD; Rfull = DD; rowbase = 0; c0 = cg * 128;
    }

    float (*tile)[64][69] = (float (*)[64][69])smem;   // two tiles, 35.3 KB
    int tx = t & 15, ty = t >> 4;
    int wc = t & 7, wr0 = t >> 3;

    // prologue: load row-band 0 into registers (512B contiguous per row)
    float4 v0[4], v1[4];
    #pragma unroll
    for (int j = 0; j < 4; ++j) {
        const float* rp = &src[(size_t)(rowbase + ty + 16 * j) * C + c0];
        v0[j] = *(const float4*)(rp + tx * 4);
        v1[j] = *(const float4*)(rp + 64 + tx * 4);
    }

    for (int it = 0; it < NIT; ++it) {
        // write current row-band into the two tiles
        #pragma unroll
        for (int j = 0; j < 4; ++j) {
            int row = ty + 16 * j;
            tile[0][row][tx * 4 + 0] = v0[j].x;
            tile[0][row][tx * 4 + 1] = v0[j].y;
            tile[0][row][tx * 4 + 2] = v0[j].z;
            tile[0][row][tx * 4 + 3] = v0[j].w;
            tile[1][row][tx * 4 + 0] = v1[j].x;
            tile[1][row][tx * 4 + 1] = v1[j].y;
            tile[1][row][tx * 4 + 2] = v1[j].z;
            tile[1][row][tx * 4 + 3] = v1[j].w;
        }
        __syncthreads();

        // prefetch next row-band into registers (covered by pack below)
        if (it + 1 < NIT) {
            #pragma unroll
            for (int j = 0; j < 4; ++j) {
                const float* rp = &src[(size_t)(rowbase + (it + 1) * 64 + ty + 16 * j) * C + c0];
                v0[j] = *(const float4*)(rp + tx * 4);
                v1[j] = *(const float4*)(rp + 64 + tx * 4);
            }
        }

        // pack + store both tiles (128B contiguous per dst row per iter)
        #pragma unroll
        for (int half = 0; half < 2; ++half) {
            #pragma unroll
            for (int p = 0; p < 2; ++p) {
                int cc = wr0 + p * 32;
                u16 pk[8];
                #pragma unroll
                for (int i = 0; i < 8; ++i)
                    pk[i] = f2bf(tile[half][wc * 8 + i][cc]);
                uint4 vv;
                vv.x = (u32)pk[0] | ((u32)pk[1] << 16);
                vv.y = (u32)pk[2] | ((u32)pk[3] << 16);
                vv.z = (u32)pk[4] | ((u32)pk[5] << 16);
                vv.w = (u32)pk[6] | ((u32)pk[7] << 16);
                *(uint4*)&dst[(size_t)(c0 + half * 64 + cc) * Rfull + rowbase + it * 64 + wc * 8] = vv;
            }
        }
        __syncthreads();
    }
}

// ---------------- routing: LDS histogram, 16 global atomics per block -------
__global__ __launch_bounds__(256) void route_kernel(
    const int* __restrict__ idxb, int* __restrict__ cnt, int* __restrict__ list)
{
    __shared__ int lcnt[GE];
    __shared__ int gbase[GE];
    int tid = threadIdx.x;
    int t = blockIdx.x * 256 + tid;
    if (tid < GE) lcnt[tid] = 0;
    __syncthreads();
    int e0 = idxb[t];
    int e1 = EE + idxb[NTOK + t];
    int r0 = atomicAdd(&lcnt[e0], 1);
    int r1 = atomicAdd(&lcnt[e1], 1);
    __syncthreads();
    if (tid < GE) {
        int c = lcnt[tid];
        gbase[tid] = c ? atomicAdd(&cnt[tid], c) : 0;
    }
    __syncthreads();
    list[(size_t)e0 * NTOK + gbase[e0] + r0] = t;
    list[(size_t)e1 * NTOK + gbase[e1] + r1] = t;
}

// ---------------- tile table (128-row granular) -----------------------------
__global__ void tilestart_kernel(const int* __restrict__ cnt, int* __restrict__ meta)
{
    int lane = threadIdx.x;   // 64 threads
    if (lane < 16) {
        int pbv = 0;
        for (int k = 0; k < lane; ++k) pbv += cnt[k];
        meta[lane] = pbv;
    }
    if (lane == 16) {
        int n = 0;
        for (int k = 0; k < 16; ++k) n += (cnt[k] + 127) >> 7;
        meta[33] = n;
    }
    for (int j = lane; j < MT128; j += 64) {
        int ge = -1, start = 0, tt = 0;
        #pragma unroll
        for (int k = 0; k < 16; ++k) {
            int mt = (cnt[k] + 127) >> 7;
            if (ge < 0) {
                if (j < start + mt) { ge = k; tt = j - start; }
                else start += mt;
            }
        }
        if (ge >= 0) meta[64 + j] = (ge << 20) | tt;
    }
}

// ---------------- 128x128 MFMA GEMM, BK=32, dbuf, counted vmcnt, 4 blk/CU ---
// Epilogue: LDS repack -> coalesced 16B stores (128B segments per row).
// MODE 0: u[pos] = gelu(h[tok] @ W1[ge] + b1[ge])      A gathered via list
// MODE 1: moe{plane}[tok] = p * (u[pos] @ W2[ge] + b2) A dense, bf16 out
template<int MODE>
__global__ __launch_bounds__(256, 4) void gemm_tile(
    const u16* __restrict__ A0, const u16* __restrict__ A1,
    const u16* __restrict__ Bt,
    const int* __restrict__ meta, const int* __restrict__ cnt,
    const int* __restrict__ list, const float* __restrict__ pbuf,
    const float* __restrict__ bias,
    u16* __restrict__ uout, u16* __restrict__ moeout)
{
    constexpr int K = (MODE == 1) ? FF : DD;
    constexpr int N = (MODE == 0) ? FF : DD;
    constexpr int NSTEP = K / 32;

    __shared__ __align__(16) u16 As[2][128 * 32];
    __shared__ __align__(16) u16 Bs[2][128 * 32];
    __shared__ int rowtok[128];
    __shared__ float rowp[128];

    int ntile = blockIdx.x;
    int j = blockIdx.y;
    if (j >= meta[33]) return;
    int ev = meta[64 + j];
    int ge = ev >> 20;
    int rb = (ev & 0xfffff) << 7;
    int cnt_e = cnt[ge];
    int pb = meta[ge];

    int tid = threadIdx.x, wave = tid >> 6, lane = tid & 63;
    int wm = wave >> 1, wn = wave & 1;
    int fr = lane & 15, fq = lane >> 4;
    int r0 = wave * 16 + (lane >> 2);
    int sc = (lane & 3) ^ ((lane >> 3) & 3);   // swizzled source chunk (bank fix)

    const u16* Abase;
    if constexpr (MODE == 0) Abase = (ge >= 8) ? A1 : A0;
    else                     Abase = A0;
    const u16* Bte = Bt + (size_t)ge * FF * DD;

    const u16 *aSrc0, *aSrc1, *bSrc0, *bSrc1;
    if constexpr (MODE == 0) {
        int lb = ge * NTOK;
        int g0 = rb + r0, g1 = g0 + 64;
        int t0 = (g0 < cnt_e) ? list[lb + g0] : list[lb];
        int t1 = (g1 < cnt_e) ? list[lb + g1] : list[lb];
        aSrc0 = Abase + (size_t)t0 * K + sc * 8;
        aSrc1 = Abase + (size_t)t1 * K + sc * 8;
    } else {
        size_t base = (size_t)(pb + rb);
        aSrc0 = Abase + (base + r0) * (size_t)K + sc * 8;
        aSrc1 = Abase + (base + r0 + 64) * (size_t)K + sc * 8;
    }
    {
        int nrow = ntile * 128 + r0;
        bSrc0 = Bte + (size_t)nrow * K + sc * 8;
        bSrc1 = Bte + (size_t)(nrow + 64) * K + sc * 8;
    }

    if constexpr (MODE == 1) {
        if (tid < 128) {
            int g = rb + tid;
            int tk = (g < cnt_e) ? list[ge * NTOK + g] : -1;
            rowtok[tid] = tk;
            rowp[tid] = (tk >= 0) ? pbuf[(ge >> 3) * NTOK + tk] : 0.f;
        }
        ASM_LGKM0;
    }

    f32v4 acc[4][4];
    #pragma unroll
    for (int mi = 0; mi < 4; ++mi)
        #pragma unroll
        for (int ni = 0; ni < 4; ++ni)
            acc[mi][ni] = (f32v4){0.f, 0.f, 0.f, 0.f};

    int ch = fq ^ ((fr >> 1) & 3);             // swizzled read chunk (bank fix)

    // ---- prologue: stage step 0 into buf 0 ----
    gload16(aSrc0, &As[0][wave * 512]);
    gload16(aSrc1, &As[0][2048 + wave * 512]);
    gload16(bSrc0, &Bs[0][wave * 512]);
    gload16(bSrc1, &Bs[0][2048 + wave * 512]);
    aSrc0 += 32; aSrc1 += 32; bSrc0 += 32; bSrc1 += 32;

    #pragma unroll 2
    for (int t = 0; t < NSTEP; ++t) {
        const int cur = t & 1;
        if (t + 1 < NSTEP) {
            gload16(aSrc0, &As[cur ^ 1][wave * 512]);
            gload16(aSrc1, &As[cur ^ 1][2048 + wave * 512]);
            gload16(bSrc0, &Bs[cur ^ 1][wave * 512]);
            gload16(bSrc1, &Bs[cur ^ 1][2048 + wave * 512]);
            aSrc0 += 32; aSrc1 += 32; bSrc0 += 32; bSrc1 += 32;
            ASM_VMCNT4;
        } else {
            ASM_VMCNT0;
        }
        bar();

        bf16v8 af[4], bfr[4];
        #pragma unroll
        for (int mi = 0; mi < 4; ++mi)
            af[mi] = *(const bf16v8*)&As[cur][(wm * 64 + mi * 16 + fr) * 32 + ch * 8];
        #pragma unroll
        for (int ni = 0; ni < 4; ++ni)
            bfr[ni] = *(const bf16v8*)&Bs[cur][(wn * 64 + ni * 16 + fr) * 32 + ch * 8];
        #pragma unroll
        for (int mi = 0; mi < 4; ++mi)
            #pragma unroll
            for (int ni = 0; ni < 4; ++ni)
                acc[mi][ni] = __builtin_amdgcn_mfma_f32_16x16x32_bf16(
                    af[mi], bfr[ni], acc[mi][ni], 0, 0, 0);
        bar();
    }

    // ---- epilogue: LDS repack -> coalesced 16B stores ----
    float bnv[4];
    #pragma unroll
    for (int ni = 0; ni < 4; ++ni)
        bnv[ni] = bias[(size_t)ge * N + ntile * 128 + wn * 64 + ni * 16 + fr];

    // halves: wm=0 waves -> As region, wm=1 waves -> Bs region; [16][133] f32
    float* halfw = (wm == 0) ? (float*)As : (float*)Bs;
    int rrd = tid >> 3;                     // 0..31: 0-15 from As, 16-31 from Bs
    const float* halfr = (rrd < 16) ? (const float*)As : (const float*)Bs;
    int lr = rrd & 15;
    int cb = (tid & 7) * 8;                 // col groups cb..cb+7 and cb+64..+71

    #pragma unroll
    for (int mi = 0; mi < 4; ++mi) {
        #pragma unroll
        for (int ni = 0; ni < 4; ++ni)
            #pragma unroll
            for (int r = 0; r < 4; ++r)
                halfw[(fq * 4 + r) * 133 + wn * 64 + ni * 16 + fr] =
                    acc[mi][ni][r] + bnv[ni];
        ASM_LGKM0;   // drain ds_writes before barrier (cross-thread RAW)
        bar();

        int grow = mi * 16 + lr + ((rrd >> 4) * 64);   // row within 128-tile
        float v0[8], v1[8];
        #pragma unroll
        for (int i = 0; i < 8; ++i) {
            v0[i] = halfr[lr * 133 + cb + i];
            v1[i] = halfr[lr * 133 + cb + 64 + i];
        }
        if constexpr (MODE == 0) {
            if (rb + grow < cnt_e) {
                u16 p0[8], p1[8];
                #pragma unroll
                for (int i = 0; i < 8; ++i) {
                    p0[i] = f2bf(gelu_tanh(v0[i]));
                    p1[i] = f2bf(gelu_tanh(v1[i]));
                }
                uint4 q0, q1;
                q0.x = (u32)p0[0] | ((u32)p0[1] << 16);
                q0.y = (u32)p0[2] | ((u32)p0[3] << 16);
                q0.z = (u32)p0[4] | ((u32)p0[5] << 16);
                q0.w = (u32)p0[6] | ((u32)p0[7] << 16);
                q1.x = (u32)p1[0] | ((u32)p1[1] << 16);
                q1.y = (u32)p1[2] | ((u32)p1[3] << 16);
                q1.z = (u32)p1[4] | ((u32)p1[5] << 16);
                q1.w = (u32)p1[6] | ((u32)p1[7] << 16);
                u16* orow = uout + (size_t)(pb + rb + grow) * FF + ntile * 128;
                *(uint4*)(orow + cb) = q0;
                *(uint4*)(orow + cb + 64) = q1;
            }
        } else {
            int tok = rowtok[grow];
            if (tok >= 0) {
                float p = rowp[grow];
                u16 p0[8], p1[8];
                #pragma unroll
                for (int i = 0; i < 8; ++i) {
                    p0[i] = f2bf(v0[i] * p);
                    p1[i] = f2bf(v1[i] * p);
                }
                uint4 q0, q1;
                q0.x = (u32)p0[0] | ((u32)p0[1] << 16);
                q0.y = (u32)p0[2] | ((u32)p0[3] << 16);
                q0.z = (u32)p0[4] | ((u32)p0[5] << 16);
                q0.w = (u32)p0[6] | ((u32)p0[7] << 16);
                q1.x = (u32)p1[0] | ((u32)p1[1] << 16);
                q1.y = (u32)p1[2] | ((u32)p1[3] << 16);
                q1.z = (u32)p1[4] | ((u32)p1[5] << 16);
                q1.w = (u32)p1[6] | ((u32)p1[7] << 16);
                u16* orow = moeout + ((size_t)(ge >> 3) * NTOK + tok) * DD + ntile * 128;
                *(uint4*)(orow + cb) = q0;
                *(uint4*)(orow + cb + 64) = q1;
            }
        }
        bar();
    }
}

// ---------------- 128x128 GEMM (output projection only) ---------------------
// dout = xres + A @ owt + out_b  (A dense bf16, f32 out, 64B segments OK)
__global__ __launch_bounds__(256, 4) void gemm_out(
    const u16* __restrict__ A0, const u16* __restrict__ Bt,
    const float* __restrict__ bias,
    const float* __restrict__ xres, float* __restrict__ dout)
{
    constexpr int K = DD;
    constexpr int NSTEP = K / 32;

    __shared__ __align__(16) u16 As[2][128 * 32];
    __shared__ __align__(16) u16 Bs[2][128 * 32];

    int ntile = blockIdx.x;
    int rb = blockIdx.y * 128;

    int tid = threadIdx.x, wave = tid >> 6, lane = tid & 63;
    int wm = wave >> 1, wn = wave & 1;
    int fr = lane & 15, fq = lane >> 4;
    int r0 = wave * 16 + (lane >> 2);
    int sc = (lane & 3) ^ ((lane >> 3) & 3);

    const u16 *aSrc0, *aSrc1, *bSrc0, *bSrc1;
    aSrc0 = A0 + (size_t)(rb + r0) * K + sc * 8;
    aSrc1 = A0 + (size_t)(rb + r0 + 64) * K + sc * 8;
    {
        int nrow = ntile * 128 + r0;
        bSrc0 = Bt + (size_t)nrow * K + sc * 8;
        bSrc1 = Bt + (size_t)(nrow + 64) * K + sc * 8;
    }

    f32v4 acc[4][4];
    #pragma unroll
    for (int mi = 0; mi < 4; ++mi)
        #pragma unroll
        for (int ni = 0; ni < 4; ++ni)
            acc[mi][ni] = (f32v4){0.f, 0.f, 0.f, 0.f};

    int ch = fq ^ ((fr >> 1) & 3);

    gload16(aSrc0, &As[0][wave * 512]);
    gload16(aSrc1, &As[0][2048 + wave * 512]);
    gload16(bSrc0, &Bs[0][wave * 512]);
    gload16(bSrc1, &Bs[0][2048 + wave * 512]);
    aSrc0 += 32; aSrc1 += 32; bSrc0 += 32; bSrc1 += 32;

    #pragma unroll 2
    for (int t = 0; t < NSTEP; ++t) {
        const int cur = t & 1;
        if (t + 1 < NSTEP) {
            gload16(aSrc0, &As[cur ^ 1][wave * 512]);
            gload16(aSrc1, &As[cur ^ 1][2048 + wave * 512]);
            gload16(bSrc0, &Bs[cur ^ 1][wave * 512]);
            gload16(bSrc1, &Bs[cur ^ 1][2048 + wave * 512]);
            aSrc0 += 32; aSrc1 += 32; bSrc0 += 32; bSrc1 += 32;
            ASM_VMCNT4;
        } else {
            ASM_VMCNT0;
        }
        bar();

        bf16v8 af[4], bfr[4];
        #pragma unroll
        for (int mi = 0; mi < 4; ++mi)
            af[mi] = *(const bf16v8*)&As[cur][(wm * 64 + mi * 16 + fr) * 32 + ch * 8];
        #pragma unroll
        for (int ni = 0; ni < 4; ++ni)
            bfr[ni] = *(const bf16v8*)&Bs[cur][(wn * 64 + ni * 16 + fr) * 32 + ch * 8];
        #pragma unroll
        for (int mi = 0; mi < 4; ++mi)
            #pragma unroll
            for (int ni = 0; ni < 4; ++ni)
                acc[mi][ni] = __builtin_amdgcn_mfma_f32_16x16x32_bf16(
                    af[mi], bfr[ni], acc[mi][ni], 0, 0, 0);
        bar();
    }

    #pragma unroll
    for (int mi = 0; mi < 4; ++mi) {
        #pragma unroll
        for (int ni = 0; ni < 4; ++ni) {
            int col = ntile * 128 + wn * 64 + ni * 16 + fr;
            float bn = bias[col];
            #pragma unroll
            for (int r = 0; r < 4; ++r) {
                int rr = wm * 64 + mi * 16 + fq * 4 + r;
                size_t o = (size_t)(rb + rr) * DD + col;
                dout[o] = xres[o] + acc[mi][ni][r] + bn;
            }
        }
    }
}

// ---------------- stylize: LN((moe0+moe1)/2)*(1+scale)+shift -> silu -> bf16
__global__ __launch_bounds__(256) void stylize_kernel(
    const u16* __restrict__ moe, const float* __restrict__ eo,
    const float* __restrict__ sn_g, const float* __restrict__ sn_b,
    u16* __restrict__ sbuf)
{
    int wave = threadIdx.x >> 6, lane = threadIdx.x & 63;
    int tok = blockIdx.x * 4 + wave;
    int b = tok / TT;
    const u16* mr = moe + (size_t)tok * DD + lane * 8;
    const u16* mr2 = mr + (size_t)NTOK * DD;
    uint4 pa = *(const uint4*)mr;
    uint4 pb = *(const uint4*)mr2;
    float os[8];
    os[0] = (bf2f(pa.x & 0xffff) + bf2f(pb.x & 0xffff)) * 0.5f;
    os[1] = (bf2f(pa.x >> 16)    + bf2f(pb.x >> 16))    * 0.5f;
    os[2] = (bf2f(pa.y & 0xffff) + bf2f(pb.y & 0xffff)) * 0.5f;
    os[3] = (bf2f(pa.y >> 16)    + bf2f(pb.y >> 16))    * 0.5f;
    os[4] = (bf2f(pa.z & 0xffff) + bf2f(pb.z & 0xffff)) * 0.5f;
    os[5] = (bf2f(pa.z >> 16)    + bf2f(pb.z >> 16))    * 0.5f;
    os[6] = (bf2f(pa.w & 0xffff) + bf2f(pb.w & 0xffff)) * 0.5f;
    os[7] = (bf2f(pa.w >> 16)    + bf2f(pb.w >> 16))    * 0.5f;
    float s = 0.f, ss = 0.f;
    #pragma unroll
    for (int i = 0; i < 8; ++i) { s += os[i]; ss += os[i] * os[i]; }
    s = wave_sum(s); ss = wave_sum(ss);
    float mu = s * (1.0f / DD);
    float var = ss * (1.0f / DD) - mu * mu;
    float rstd = rsqrtf(var + 1e-5f);
    u16 hu[8];
    #pragma unroll
    for (int i = 0; i < 8; ++i) {
        int d = lane * 8 + i;
        float h = (os[i] - mu) * rstd * sn_g[d] + sn_b[d];
        float scv = eo[(size_t)b * 1024 + d];
        float shv = eo[(size_t)b * 1024 + DD + d];
        h = h * (1.0f + scv) + shv;
        hu[i] = f2bf(silu(h));
    }
    uint4 pk;
    pk.x = (u32)hu[0] | ((u32)hu[1] << 16);
    pk.y = (u32)hu[2] | ((u32)hu[3] << 16);
    pk.z = (u32)hu[4] | ((u32)hu[5] << 16);
    pk.w = (u32)hu[6] | ((u32)hu[7] << 16);
    *(uint4*)(sbuf + (size_t)tok * DD + lane * 8) = pk;
}

// ---------------- host ----------------
extern "C" void kernel_launch(void* const* d_in, const int* in_sizes, int n_in,
                              void* d_out, int out_size, void* d_ws, size_t ws_size,
                              hipStream_t stream)
{
    const float* x      = (const float*)d_in[0];
    const float* emb    = (const float*)d_in[1];
    const float* ln_g   = (const float*)d_in[2];
    const float* ln_b   = (const float*)d_in[3];
    const float* gate_w = (const float*)d_in[4];
    const float* gate_b = (const float*)d_in[5];
    const float* w1     = (const float*)d_in[6];
    const float* b1     = (const float*)d_in[7];
    const float* w2     = (const float*)d_in[8];
    const float* b2     = (const float*)d_in[9];
    const float* emb_w  = (const float*)d_in[10];
    const float* emb_b  = (const float*)d_in[11];
    const float* sn_g   = (const float*)d_in[12];
    const float* sn_b   = (const float*)d_in[13];
    const float* out_w  = (const float*)d_in[14];
    const float* out_b  = (const float*)d_in[15];
    (void)n_in; (void)in_sizes; (void)out_size; (void)ws_size;

    const size_t szW    = (size_t)GE * FF * DD * 2;
    const size_t szOwt  = (size_t)DD * DD * 2;
    const size_t szH    = (size_t)NTOK * DD * 2;
    const size_t szEo   = (size_t)BB * 2 * DD * 4;
    const size_t szP    = (size_t)NBR * NTOK * 4;
    const size_t szCnt  = 256, szMeta = 4096;
    const size_t szList = (size_t)GE * NTOK * 4;
    const size_t szU    = ((size_t)2 * NTOK + 256) * FF * 2;
    const size_t szM    = (size_t)2 * NTOK * DD * 2;

    auto align256 = [](size_t v) { return (v + 255) & ~(size_t)255; };
    char* w = (char*)d_ws;
    size_t off = 0;
    auto take = [&](size_t bytes) -> void* {
        void* p = w + off;
        off = align256(off + bytes);
        return p;
    };
    u16*   w1t  = (u16*)take(szW);
    u16*   w2t  = (u16*)take(szW);
    u16*   owt  = (u16*)take(szOwt);
    u16*   hA   = (u16*)take(szH);       // reused as sbuf
    u16*   hB   = (u16*)take(szH);
    float* eo   = (float*)take(szEo);
    float* pbuf = (float*)take(szP);
    int*   idxb = (int*)take(szP);
    int*   cnt  = (int*)take(szCnt);
    int*   meta = (int*)take(szMeta);
    int*   list = (int*)take(szList);
    u16*   ubuf = (u16*)take(szU);
    u16*   moe  = (u16*)take(szM);

    // 1. merged front: slab transposes + eo + cnt init + LN/gate
    front_kernel<<<NB_FRONT, 256, 0, stream>>>(w1, w1t, w2, w2t, out_w, owt,
                                               emb, emb_w, emb_b, eo, cnt,
                                               x, ln_g, ln_b, gate_w, gate_b,
                                               hA, hB, idxb, pbuf);

    // 2. routing (LDS histogram) + tile table
    route_kernel<<<NTOK / 256, 256, 0, stream>>>(idxb, cnt, list);
    tilestart_kernel<<<1, 64, 0, stream>>>(cnt, meta);

    // 3. expert FFN (flat tile queues, ntile-fastest)
    gemm_tile<0><<<dim3(FF / 128, MT128), 256, 0, stream>>>(
        hA, hB, w1t, meta, cnt, list, nullptr, b1, ubuf, nullptr);
    gemm_tile<1><<<dim3(DD / 128, MT128), 256, 0, stream>>>(
        ubuf, nullptr, w2t, meta, cnt, list, pbuf, b2, nullptr, moe);

    // 4. stylization + output projection + residual
    stylize_kernel<<<NTOK / 4, 256, 0, stream>>>(moe, eo, sn_g, sn_b, hA);
    gemm_out<<<dim3(DD / 128, NTOK / 128), 256, 0, stream>>>(
        hA, owt, out_b, x, (float*)d_out);
}